// Round 5
// baseline (165.590 us; speedup 1.0000x reference)
//
#include <hip/hip_runtime.h>

// LSTM (B=8192, T=168, F=64, H=50) + MLP head, fused, f16 MFMA + fp32 state.
// Round 5: round-4 structure + fence-minimal in-loop barriers
// (s_waitcnt lgkmcnt(0); s_barrier — NO vmcnt drain). Round 4's limiter:
// __syncthreads() drains vmcnt(0) every step, serializing the x prefetch's
// HBM latency into the critical path. With lgkm-only barriers the 2-step-deep
// register prefetch actually floats across barriers.

#define B_N 8192
#define T_N 168
#define F_N 64
#define H_N 50
#define HEAD_N 100
#define ROWSTRIDE (T_N * F_N)  // 10752

typedef _Float16 f16x8 __attribute__((ext_vector_type(8)));
typedef _Float16 f16x4 __attribute__((ext_vector_type(4)));
typedef float    f32x4 __attribute__((ext_vector_type(4)));

#define LOG2E  1.4426950408889634f
#define LOG2E2 2.8853900817779268f

#define MFMA __builtin_amdgcn_mfma_f32_16x16x32_f16

// LDS-only barrier: drain own LDS ops, barrier, compiler fence both sides.
// (s_barrier builtin is convergent but NOT an LLVM memory fence; the
// "memory"-clobbered asms pin ds ops on the correct side. vmcnt deliberately
// NOT drained: register-destined global prefetch stays in flight.)
#define BAR()                                                        \
    do {                                                             \
        asm volatile("s_waitcnt lgkmcnt(0)" ::: "memory");           \
        __builtin_amdgcn_s_barrier();                                \
        asm volatile("" ::: "memory");                               \
    } while (0)

__device__ __forceinline__ float rcp_f(float v) { return __builtin_amdgcn_rcpf(v); }
#if __has_builtin(__builtin_amdgcn_exp2f)
__device__ __forceinline__ float exp2_f(float v) { return __builtin_amdgcn_exp2f(v); }
#else
__device__ __forceinline__ float exp2_f(float v) { return __expf(0.6931471805599453f * v); }
#endif

__launch_bounds__(256, 2)
__global__ void lstm_fused(const float* __restrict__ x,
                           const float* __restrict__ Wx,
                           const float* __restrict__ Wh,
                           const float* __restrict__ b,
                           const float* __restrict__ W1,
                           const float* __restrict__ b1,
                           const float* __restrict__ W2,
                           const float* __restrict__ b2,
                           float* __restrict__ out)
{
    // stride 72 f16 (144 B): rows 16B-aligned, worst 2-way bank alias (free)
    __shared__ alignas(16) _Float16 xb[2][16][72];  // xb[t&1] holds x(t)
    __shared__ alignas(16) _Float16 hb[2][16][72];  // hb[t&1] holds h(t)
    __shared__ float hrelu[16][HEAD_N];

    const int tid  = threadIdx.x;
    const int lane = tid & 63;
    const int w    = tid >> 6;        // wave id = unit-tile (16 units each)
    const int rowA = lane & 15;       // A-frag row == C-frag col
    const int kg   = lane >> 4;       // k-group 0..3
    const int R0   = blockIdx.x * 16; // batch rows of this block

    // ---- weight B-fragments (VGPR-resident), prescaled to exp2 domain -----
    // col256 = g*64 + j ; this wave: j in [16w, 16w+16)
    f16x8 wxf[4][2], whf[4][2];
    float bg[4];
    const int  jl = w * 16 + rowA;    // unit index 0..63 (lane's column)
    const bool jv = (jl < H_N);
    #pragma unroll
    for (int g = 0; g < 4; ++g) {
        const float sc = (g == 2) ? LOG2E2 : LOG2E;   // g-gate: fold tanh's 2x
        bg[g] = jv ? b[g * H_N + jl] * sc : 0.0f;
        #pragma unroll
        for (int ks = 0; ks < 2; ++ks) {
            f16x8 vx, vh;
            #pragma unroll
            for (int i = 0; i < 8; ++i) {
                int k = ks * 32 + kg * 8 + i;   // same k-map for A & B -> cancels
                float xv = 0.0f, hv = 0.0f;
                if (jv)            xv = Wx[k * 200 + g * H_N + jl] * sc;
                if (jv && k < H_N) hv = Wh[k * 200 + g * H_N + jl] * sc;
                vx[i] = (_Float16)xv;
                vh[i] = (_Float16)hv;
            }
            wxf[g][ks] = vx;
            whf[g][ks] = vh;
        }
    }

    float c0 = 0.f, c1 = 0.f, c2 = 0.f, c3 = 0.f;  // fp32 cell state

    // zero h(0)
    for (int idx = tid; idx < 16 * 72; idx += 256)
        ((_Float16*)hb[0])[idx] = (_Float16)0.0f;

    // x staging map: thread -> (row tid>>4, 4 floats), coalesced 256B/row
    const int xr  = tid >> 4;
    const int xf0 = (tid & 15) * 4;
    const float* xrow = x + (size_t)(R0 + xr) * ROWSTRIDE + xf0;

    f32x4 xpr0, xpr1;   // in-flight x rows: xpr[t&1] written to LDS at step t
    {
        f32x4 v0 = *reinterpret_cast<const f32x4*>(xrow);
        f32x4 v1 = *reinterpret_cast<const f32x4*>(xrow + F_N);
        xpr0 = *reinterpret_cast<const f32x4*>(xrow + 2 * F_N);   // x(2)
        xpr1 = *reinterpret_cast<const f32x4*>(xrow + 3 * F_N);   // x(3)
        f16x4 a, c4;
        #pragma unroll
        for (int j = 0; j < 4; ++j) { a[j] = (_Float16)v0[j]; c4[j] = (_Float16)v1[j]; }
        *reinterpret_cast<f16x4*>(&xb[0][xr][xf0]) = a;   // x(0)
        *reinterpret_cast<f16x4*>(&xb[1][xr][xf0]) = c4;  // x(1)
    }
    const float* xld = xrow + 4 * F_N;   // next global load: x(4)
    __syncthreads();

    // ax = b + x(0) @ Wx  (precompute for step 0)
    f32x4 axi, axf, axg, axo;
    {
        f16x8 xa0 = *reinterpret_cast<const f16x8*>(&xb[0][rowA][kg * 8]);
        f16x8 xa1 = *reinterpret_cast<const f16x8*>(&xb[0][rowA][32 + kg * 8]);
        axi = (f32x4){bg[0], bg[0], bg[0], bg[0]};
        axf = (f32x4){bg[1], bg[1], bg[1], bg[1]};
        axg = (f32x4){bg[2], bg[2], bg[2], bg[2]};
        axo = (f32x4){bg[3], bg[3], bg[3], bg[3]};
        axi = MFMA(xa0, wxf[0][0], axi, 0, 0, 0);
        axf = MFMA(xa0, wxf[1][0], axf, 0, 0, 0);
        axg = MFMA(xa0, wxf[2][0], axg, 0, 0, 0);
        axo = MFMA(xa0, wxf[3][0], axo, 0, 0, 0);
        axi = MFMA(xa1, wxf[0][1], axi, 0, 0, 0);
        axf = MFMA(xa1, wxf[1][1], axf, 0, 0, 0);
        axg = MFMA(xa1, wxf[2][1], axg, 0, 0, 0);
        axo = MFMA(xa1, wxf[3][1], axo, 0, 0, 0);
    }
    __syncthreads();   // step 0 overwrites xb[0]; protect the reads above

    // gate: all-exp2-domain; writes h(t+1) f16 into hb[PW]
#define GATE1(PW, ii, cvar)                                                    \
    {                                                                          \
        float si_ = rcp_f(1.0f + exp2_f(-zi[ii]));                             \
        float sf_ = rcp_f(1.0f + exp2_f(-zf[ii]));                             \
        float tg_ = fmaf(-2.0f, rcp_f(1.0f + exp2_f(zg[ii])), 1.0f);           \
        float so_ = rcp_f(1.0f + exp2_f(-zo[ii]));                             \
        float cn_ = fmaf(sf_, cvar, si_ * tg_);                                \
        cvar = cn_;                                                            \
        float tc_ = fmaf(-2.0f, rcp_f(1.0f + exp2_f(LOG2E2 * cn_)), 1.0f);     \
        hb[PW][kg * 4 + ii][jl] = (_Float16)(so_ * tc_);                       \
    }

    // One step t (P = t&1): z = ax + h(t)@Wh ; ax' = b + x(t+1)@Wx (off-path);
    // LDS-write x(t+2) from reg; issue load x(t+4); gates; write h(t+1);
    // LDS-only barrier (x prefetch loads stay in flight across it).
#define STEP(P, DO_XF, DO_XW, DO_LOAD)                                         \
    {                                                                          \
        f16x8 ha0 = *reinterpret_cast<const f16x8*>(&hb[P][rowA][kg * 8]);     \
        f16x8 ha1 = *reinterpret_cast<const f16x8*>(&hb[P][rowA][32 + kg * 8]);\
        f32x4 zi = MFMA(ha0, whf[0][0], axi, 0, 0, 0);                         \
        f32x4 zf = MFMA(ha0, whf[1][0], axf, 0, 0, 0);                         \
        f32x4 zg = MFMA(ha0, whf[2][0], axg, 0, 0, 0);                         \
        f32x4 zo = MFMA(ha0, whf[3][0], axo, 0, 0, 0);                         \
        zi = MFMA(ha1, whf[0][1], zi, 0, 0, 0);                                \
        zf = MFMA(ha1, whf[1][1], zf, 0, 0, 0);                                \
        zg = MFMA(ha1, whf[2][1], zg, 0, 0, 0);                                \
        zo = MFMA(ha1, whf[3][1], zo, 0, 0, 0);                                \
        if (DO_XF) {  /* ax for step t+1 from x(t+1) in xb[P^1] */             \
            f16x8 xa0 = *reinterpret_cast<const f16x8*>(&xb[P ^ 1][rowA][kg * 8]);      \
            f16x8 xa1 = *reinterpret_cast<const f16x8*>(&xb[P ^ 1][rowA][32 + kg * 8]); \
            axi = (f32x4){bg[0], bg[0], bg[0], bg[0]};                         \
            axf = (f32x4){bg[1], bg[1], bg[1], bg[1]};                         \
            axg = (f32x4){bg[2], bg[2], bg[2], bg[2]};                         \
            axo = (f32x4){bg[3], bg[3], bg[3], bg[3]};                         \
            axi = MFMA(xa0, wxf[0][0], axi, 0, 0, 0);                          \
            axf = MFMA(xa0, wxf[1][0], axf, 0, 0, 0);                          \
            axg = MFMA(xa0, wxf[2][0], axg, 0, 0, 0);                          \
            axo = MFMA(xa0, wxf[3][0], axo, 0, 0, 0);                          \
            axi = MFMA(xa1, wxf[0][1], axi, 0, 0, 0);                          \
            axf = MFMA(xa1, wxf[1][1], axf, 0, 0, 0);                          \
            axg = MFMA(xa1, wxf[2][1], axg, 0, 0, 0);                          \
            axo = MFMA(xa1, wxf[3][1], axo, 0, 0, 0);                          \
        }                                                                      \
        if (DO_XW) {  /* x(t+2) -> xb[P]; its frags were read at step t-1 */   \
            f16x4 xc;                                                          \
            xc[0] = (_Float16)xpr##P[0]; xc[1] = (_Float16)xpr##P[1];          \
            xc[2] = (_Float16)xpr##P[2]; xc[3] = (_Float16)xpr##P[3];          \
            *reinterpret_cast<f16x4*>(&xb[P][xr][xf0]) = xc;                   \
        }                                                                      \
        if (DO_LOAD) { xpr##P = *reinterpret_cast<const f32x4*>(xld); xld += F_N; } \
        GATE1(P ^ 1, 0, c0)                                                    \
        GATE1(P ^ 1, 1, c1)                                                    \
        GATE1(P ^ 1, 2, c2)                                                    \
        GATE1(P ^ 1, 3, c3)                                                    \
        BAR();                                                                 \
    }

    // t = 0..163 main, then peel 164..167 (drop loads/writes/frags at the edge)
    for (int it = 0; it < 82; ++it) {
        STEP(0, 1, 1, 1)
        STEP(1, 1, 1, 1)
    }
    STEP(0, 1, 1, 0)   // t=164: writes x(166)
    STEP(1, 1, 1, 0)   // t=165: writes x(167)
    STEP(0, 1, 0, 0)   // t=166: last ax precompute (x(167))
    STEP(1, 0, 0, 0)   // t=167: final -> h(168) in hb[0]
#undef STEP
#undef GATE1

    // ---- MLP head: relu(h@W1 + b1)@W2 + b2 + x[:, -1, 0] ------------------
    {
        const int r1 = tid & 15;
        const int u1 = tid >> 4;
        float hrow[H_N];
        #pragma unroll
        for (int k = 0; k < H_N; ++k) hrow[k] = (float)hb[0][r1][k];
        for (int uu = u1; uu < HEAD_N; uu += 16) {
            float s = b1[uu];
            #pragma unroll
            for (int k = 0; k < H_N; ++k) s += hrow[k] * W1[k * HEAD_N + uu];
            hrelu[r1][uu] = fmaxf(s, 0.0f);
        }
    }
    __syncthreads();
    {
        const int r2 = tid >> 4;
        const int p  = tid & 15;
        float s = 0.0f;
        for (int uu = p; uu < HEAD_N; uu += 16) s += hrelu[r2][uu] * W2[uu];
        #pragma unroll
        for (int off = 8; off > 0; off >>= 1) s += __shfl_xor(s, off, 16);
        if (p == 0) {
            float res = x[(size_t)(R0 + r2) * ROWSTRIDE + (T_N - 1) * F_N + 0];
            out[R0 + r2] = s + b2[0] + res;
        }
    }
}

extern "C" void kernel_launch(void* const* d_in, const int* in_sizes, int n_in,
                              void* d_out, int out_size, void* d_ws, size_t ws_size,
                              hipStream_t stream) {
    const float* x  = (const float*)d_in[0];
    const float* Wx = (const float*)d_in[1];
    const float* Wh = (const float*)d_in[2];
    const float* b  = (const float*)d_in[3];
    const float* W1 = (const float*)d_in[4];
    const float* b1 = (const float*)d_in[5];
    const float* W2 = (const float*)d_in[6];
    const float* b2 = (const float*)d_in[7];
    float* out = (float*)d_out;

    lstm_fused<<<dim3(B_N / 16), dim3(256), 0, stream>>>(x, Wx, Wh, b, W1, b1, W2, b2, out);
}

// Round 6
// 151.755 us; speedup vs baseline: 1.0912x; 1.0912x over previous
//
#include <hip/hip_runtime.h>

// LSTM (B=8192, T=168, F=64, H=50) + MLP head, fused, f16 MFMA + fp32 state.
// Round 6: producer/consumer wave specialization. 512-thread blocks:
// waves 0-3 (x-waves) compute ax(t+1)=b+x(t+1)@Wx into LDS (C-frag layout)
// + all x staging/prefetch; waves 4-7 (h-waves) do ds_read h/ax -> 8 MFMA ->
// gates -> write h. 2 blocks/CU -> 4 waves/SIMD (was 2), desynchronized
// roles; h critical path minimized; setprio(1) on consumers.

#define B_N 8192
#define T_N 168
#define F_N 64
#define H_N 50
#define HEAD_N 100
#define ROWSTRIDE (T_N * F_N)  // 10752

typedef _Float16 f16x8 __attribute__((ext_vector_type(8)));
typedef _Float16 f16x4 __attribute__((ext_vector_type(4)));
typedef float    f32x4 __attribute__((ext_vector_type(4)));

#define LOG2E  1.4426950408889634f
#define LOG2E2 2.8853900817779268f

#define MFMA __builtin_amdgcn_mfma_f32_16x16x32_f16

// LDS-only barrier: drain own LDS ops, barrier, compiler fence both sides.
// vmcnt NOT drained: register-destined global prefetch stays in flight.
#define BAR()                                                        \
    do {                                                             \
        asm volatile("s_waitcnt lgkmcnt(0)" ::: "memory");           \
        __builtin_amdgcn_s_barrier();                                \
        asm volatile("" ::: "memory");                               \
    } while (0)

__device__ __forceinline__ float rcp_f(float v) { return __builtin_amdgcn_rcpf(v); }
#if __has_builtin(__builtin_amdgcn_exp2f)
__device__ __forceinline__ float exp2_f(float v) { return __builtin_amdgcn_exp2f(v); }
#else
__device__ __forceinline__ float exp2_f(float v) { return __expf(0.6931471805599453f * v); }
#endif

__launch_bounds__(512, 4)
__global__ void lstm_fused(const float* __restrict__ x,
                           const float* __restrict__ Wx,
                           const float* __restrict__ Wh,
                           const float* __restrict__ b,
                           const float* __restrict__ W1,
                           const float* __restrict__ b1,
                           const float* __restrict__ W2,
                           const float* __restrict__ b2,
                           float* __restrict__ out)
{
    __shared__ alignas(16) _Float16 xb[2][16][72];        // xb[t&1] = x(t)
    __shared__ alignas(16) _Float16 hb[2][16][72];        // hb[t&1] = h(t)
    __shared__ alignas(16) float axb[2][4][4][64][4];     // [P][tile][gate][lane][4]
    __shared__ float hrelu[16][HEAD_N];

    const int tid  = threadIdx.x;
    const int lane = tid & 63;
    const int w    = tid >> 6;         // 0..7; 0-3 x-waves, 4-7 h-waves
    const int ut   = w & 3;            // unit-tile (16 units each)
    const int rowA = lane & 15;        // A-frag row == C-frag col
    const int kg   = lane >> 4;        // k-group 0..3
    const int R0   = blockIdx.x * 16;  // batch rows of this block
    const int jl   = ut * 16 + rowA;   // unit index 0..63
    const bool jv  = (jl < H_N);

    // ---- role-specific weight fragments (VGPR-resident, exp2-prescaled) --
    f16x8 wxf[4][2], whf[4][2];
    float bg[4];
    if (w < 4) {
        #pragma unroll
        for (int g = 0; g < 4; ++g) {
            const float sc = (g == 2) ? LOG2E2 : LOG2E;
            bg[g] = jv ? b[g * H_N + jl] * sc : 0.0f;
            #pragma unroll
            for (int ks = 0; ks < 2; ++ks) {
                f16x8 v;
                #pragma unroll
                for (int i = 0; i < 8; ++i) {
                    int k = ks * 32 + kg * 8 + i;     // same k-map as A-frags
                    v[i] = (_Float16)(jv ? Wx[k * 200 + g * H_N + jl] * sc : 0.0f);
                }
                wxf[g][ks] = v;
            }
        }
    } else {
        #pragma unroll
        for (int g = 0; g < 4; ++g) {
            const float sc = (g == 2) ? LOG2E2 : LOG2E;
            #pragma unroll
            for (int ks = 0; ks < 2; ++ks) {
                f16x8 v;
                #pragma unroll
                for (int i = 0; i < 8; ++i) {
                    int k = ks * 32 + kg * 8 + i;
                    v[i] = (_Float16)((jv && k < H_N) ? Wh[k * 200 + g * H_N + jl] * sc : 0.0f);
                }
                whf[g][ks] = v;
            }
        }
    }

    float c0 = 0.f, c1 = 0.f, c2 = 0.f, c3 = 0.f;   // h-wave fp32 cell state

    // zero h(0)
    for (int idx = tid; idx < 16 * 72; idx += 512)
        ((_Float16*)hb[0])[idx] = (_Float16)0.0f;

    // x staging map (x-waves = tid 0..255): (row tid>>4, 4 floats), coalesced
    const int xr  = (tid >> 4) & 15;
    const int xf0 = (tid & 15) * 4;
    const float* xrow = x + (size_t)(R0 + xr) * ROWSTRIDE + xf0;
    f32x4 xpr0, xpr1;     // in-flight x rows: xpr[t&1] LDS-written at step t
    if (w < 4) {
        f32x4 v0 = *reinterpret_cast<const f32x4*>(xrow);
        f32x4 v1 = *reinterpret_cast<const f32x4*>(xrow + F_N);
        xpr0 = *reinterpret_cast<const f32x4*>(xrow + 2 * F_N);   // x(2)
        xpr1 = *reinterpret_cast<const f32x4*>(xrow + 3 * F_N);   // x(3)
        f16x4 a, c4;
        #pragma unroll
        for (int j = 0; j < 4; ++j) { a[j] = (_Float16)v0[j]; c4[j] = (_Float16)v1[j]; }
        *reinterpret_cast<f16x4*>(&xb[0][xr][xf0]) = a;   // x(0)
        *reinterpret_cast<f16x4*>(&xb[1][xr][xf0]) = c4;  // x(1)
    }
    const float* xld = xrow + 4 * F_N;   // next global load: x(4)
    __syncthreads();

    if (w < 4) {   // prologue: ax(0) = b + x(0)@Wx -> axb[0]
        f16x8 xa0 = *reinterpret_cast<const f16x8*>(&xb[0][rowA][kg * 8]);
        f16x8 xa1 = *reinterpret_cast<const f16x8*>(&xb[0][rowA][32 + kg * 8]);
        f32x4 a0 = {bg[0], bg[0], bg[0], bg[0]};
        f32x4 a1 = {bg[1], bg[1], bg[1], bg[1]};
        f32x4 a2 = {bg[2], bg[2], bg[2], bg[2]};
        f32x4 a3 = {bg[3], bg[3], bg[3], bg[3]};
        a0 = MFMA(xa0, wxf[0][0], a0, 0, 0, 0);
        a1 = MFMA(xa0, wxf[1][0], a1, 0, 0, 0);
        a2 = MFMA(xa0, wxf[2][0], a2, 0, 0, 0);
        a3 = MFMA(xa0, wxf[3][0], a3, 0, 0, 0);
        a0 = MFMA(xa1, wxf[0][1], a0, 0, 0, 0);
        a1 = MFMA(xa1, wxf[1][1], a1, 0, 0, 0);
        a2 = MFMA(xa1, wxf[2][1], a2, 0, 0, 0);
        a3 = MFMA(xa1, wxf[3][1], a3, 0, 0, 0);
        *reinterpret_cast<f32x4*>(&axb[0][ut][0][lane][0]) = a0;
        *reinterpret_cast<f32x4*>(&axb[0][ut][1][lane][0]) = a1;
        *reinterpret_cast<f32x4*>(&axb[0][ut][2][lane][0]) = a2;
        *reinterpret_cast<f32x4*>(&axb[0][ut][3][lane][0]) = a3;
    }
    __syncthreads();

    // gates: exp2-domain; writes h(t+1) f16 into hb[PW]
#define GATE1(PW, ii, cvar)                                                    \
    {                                                                          \
        float si_ = rcp_f(1.0f + exp2_f(-zi[ii]));                             \
        float sf_ = rcp_f(1.0f + exp2_f(-zf[ii]));                             \
        float tg_ = fmaf(-2.0f, rcp_f(1.0f + exp2_f(zg[ii])), 1.0f);           \
        float so_ = rcp_f(1.0f + exp2_f(-zo[ii]));                             \
        float cn_ = fmaf(sf_, cvar, si_ * tg_);                                \
        cvar = cn_;                                                            \
        float tc_ = fmaf(-2.0f, rcp_f(1.0f + exp2_f(LOG2E2 * cn_)), 1.0f);     \
        hb[PW][kg * 4 + ii][jl] = (_Float16)(so_ * tc_);                       \
    }

    // x-wave step t (P=t&1): ax(t+1) -> axb[P^1] (reads xb[P^1] = x(t+1));
    // LDS-write x(t+2) -> xb[P]; issue load x(t+4); barrier.
#define XSTEP(P, DO_XW, DO_LOAD)                                               \
    {                                                                          \
        f16x8 xa0 = *reinterpret_cast<const f16x8*>(&xb[P ^ 1][rowA][kg * 8]);      \
        f16x8 xa1 = *reinterpret_cast<const f16x8*>(&xb[P ^ 1][rowA][32 + kg * 8]); \
        f32x4 a0 = {bg[0], bg[0], bg[0], bg[0]};                               \
        f32x4 a1 = {bg[1], bg[1], bg[1], bg[1]};                               \
        f32x4 a2 = {bg[2], bg[2], bg[2], bg[2]};                               \
        f32x4 a3 = {bg[3], bg[3], bg[3], bg[3]};                               \
        a0 = MFMA(xa0, wxf[0][0], a0, 0, 0, 0);                                \
        a1 = MFMA(xa0, wxf[1][0], a1, 0, 0, 0);                                \
        a2 = MFMA(xa0, wxf[2][0], a2, 0, 0, 0);                                \
        a3 = MFMA(xa0, wxf[3][0], a3, 0, 0, 0);                                \
        a0 = MFMA(xa1, wxf[0][1], a0, 0, 0, 0);                                \
        a1 = MFMA(xa1, wxf[1][1], a1, 0, 0, 0);                                \
        a2 = MFMA(xa1, wxf[2][1], a2, 0, 0, 0);                                \
        a3 = MFMA(xa1, wxf[3][1], a3, 0, 0, 0);                                \
        *reinterpret_cast<f32x4*>(&axb[P ^ 1][ut][0][lane][0]) = a0;           \
        *reinterpret_cast<f32x4*>(&axb[P ^ 1][ut][1][lane][0]) = a1;           \
        *reinterpret_cast<f32x4*>(&axb[P ^ 1][ut][2][lane][0]) = a2;           \
        *reinterpret_cast<f32x4*>(&axb[P ^ 1][ut][3][lane][0]) = a3;           \
        if (DO_XW) {                                                           \
            f16x4 xc;                                                          \
            xc[0] = (_Float16)xpr##P[0]; xc[1] = (_Float16)xpr##P[1];          \
            xc[2] = (_Float16)xpr##P[2]; xc[3] = (_Float16)xpr##P[3];          \
            *reinterpret_cast<f16x4*>(&xb[P][xr][xf0]) = xc;                   \
        }                                                                      \
        if (DO_LOAD) { xpr##P = *reinterpret_cast<const f32x4*>(xld); xld += F_N; } \
        BAR();                                                                 \
    }

    // h-wave step t (P=t&1): z = axb[P] + h(t)@Wh; gates; h(t+1) -> hb[P^1].
#define HSTEP(P)                                                               \
    {                                                                          \
        __builtin_amdgcn_s_setprio(1);                                         \
        f16x8 ha0 = *reinterpret_cast<const f16x8*>(&hb[P][rowA][kg * 8]);     \
        f16x8 ha1 = *reinterpret_cast<const f16x8*>(&hb[P][rowA][32 + kg * 8]);\
        f32x4 zi = *reinterpret_cast<const f32x4*>(&axb[P][ut][0][lane][0]);   \
        f32x4 zf = *reinterpret_cast<const f32x4*>(&axb[P][ut][1][lane][0]);   \
        f32x4 zg = *reinterpret_cast<const f32x4*>(&axb[P][ut][2][lane][0]);   \
        f32x4 zo = *reinterpret_cast<const f32x4*>(&axb[P][ut][3][lane][0]);   \
        zi = MFMA(ha0, whf[0][0], zi, 0, 0, 0);                                \
        zf = MFMA(ha0, whf[1][0], zf, 0, 0, 0);                                \
        zg = MFMA(ha0, whf[2][0], zg, 0, 0, 0);                                \
        zo = MFMA(ha0, whf[3][0], zo, 0, 0, 0);                                \
        zi = MFMA(ha1, whf[0][1], zi, 0, 0, 0);                                \
        zf = MFMA(ha1, whf[1][1], zf, 0, 0, 0);                                \
        zg = MFMA(ha1, whf[2][1], zg, 0, 0, 0);                                \
        zo = MFMA(ha1, whf[3][1], zo, 0, 0, 0);                                \
        GATE1(P ^ 1, 0, c0)                                                    \
        GATE1(P ^ 1, 1, c1)                                                    \
        GATE1(P ^ 1, 2, c2)                                                    \
        GATE1(P ^ 1, 3, c3)                                                    \
        __builtin_amdgcn_s_setprio(0);                                         \
        BAR();                                                                 \
    }

    // Both role-loops execute EXACTLY 168 barriers (mirror structure).
    if (w < 4) {
        for (int it = 0; it < 82; ++it) {   // t = 0..163
            XSTEP(0, 1, 1)
            XSTEP(1, 1, 1)
        }
        XSTEP(0, 1, 0)   // t=164: ax(165), write x(166)
        XSTEP(1, 1, 0)   // t=165: ax(166), write x(167)
        XSTEP(0, 0, 0)   // t=166: ax(167)
        BAR();           // t=167: x-waves just sync
    } else {
        for (int it = 0; it < 82; ++it) {   // t = 0..163
            HSTEP(0)
            HSTEP(1)
        }
        HSTEP(0)   // t=164
        HSTEP(1)   // t=165
        HSTEP(0)   // t=166
        HSTEP(1)   // t=167: final h(168) -> hb[0]
    }
#undef XSTEP
#undef HSTEP
#undef GATE1

    // ---- MLP head: relu(h@W1 + b1)@W2 + b2 + x[:, -1, 0] ------------------
    if (tid < 256) {
        const int r1 = tid & 15;
        const int u1 = tid >> 4;
        float hrow[H_N];
        #pragma unroll
        for (int k = 0; k < H_N; ++k) hrow[k] = (float)hb[0][r1][k];
        for (int uu = u1; uu < HEAD_N; uu += 16) {
            float s = b1[uu];
            #pragma unroll
            for (int k = 0; k < H_N; ++k) s += hrow[k] * W1[k * HEAD_N + uu];
            hrelu[r1][uu] = fmaxf(s, 0.0f);
        }
    }
    __syncthreads();
    if (tid < 256) {
        const int r2 = tid >> 4;
        const int p  = tid & 15;
        float s = 0.0f;
        for (int uu = p; uu < HEAD_N; uu += 16) s += hrelu[r2][uu] * W2[uu];
        #pragma unroll
        for (int off = 8; off > 0; off >>= 1) s += __shfl_xor(s, off, 16);
        if (p == 0) {
            float res = x[(size_t)(R0 + r2) * ROWSTRIDE + (T_N - 1) * F_N + 0];
            out[R0 + r2] = s + b2[0] + res;
        }
    }
}

extern "C" void kernel_launch(void* const* d_in, const int* in_sizes, int n_in,
                              void* d_out, int out_size, void* d_ws, size_t ws_size,
                              hipStream_t stream) {
    const float* x  = (const float*)d_in[0];
    const float* Wx = (const float*)d_in[1];
    const float* Wh = (const float*)d_in[2];
    const float* b  = (const float*)d_in[3];
    const float* W1 = (const float*)d_in[4];
    const float* b1 = (const float*)d_in[5];
    const float* W2 = (const float*)d_in[6];
    const float* b2 = (const float*)d_in[7];
    float* out = (float*)d_out;

    lstm_fused<<<dim3(B_N / 16), dim3(512), 0, stream>>>(x, Wx, Wh, b, W1, b1, W2, b2, out);
}

// Round 7
// 151.710 us; speedup vs baseline: 1.0915x; 1.0003x over previous
//
#include <hip/hip_runtime.h>

// LSTM (B=8192, T=168, F=64, H=50) + MLP head, fused, f16 MFMA + fp32 state.
// Round 7: round-6 structure (producer/consumer wave split, 1 lgkm-barrier
// per step) + gate math v2: merged-reciprocal gate pairs
//   sigm(i)*tanh(g) = (1-B)/((1+A)(1+B)),  A=e^-i, B=e^-2g
//   sigm(o)*tanh(c) = (1-D)/((1+C)(1+D)),  C=e^-o, D=e^-2c (fmin-guarded)
// -> 8 trans/cell instead of 10 (5 exp2 + 3 rcp).

#define B_N 8192
#define T_N 168
#define F_N 64
#define H_N 50
#define HEAD_N 100
#define ROWSTRIDE (T_N * F_N)  // 10752

typedef _Float16 f16x8 __attribute__((ext_vector_type(8)));
typedef _Float16 f16x4 __attribute__((ext_vector_type(4)));
typedef float    f32x4 __attribute__((ext_vector_type(4)));

#define LOG2E  1.4426950408889634f
#define LOG2E2 2.8853900817779268f

#define MFMA __builtin_amdgcn_mfma_f32_16x16x32_f16

// LDS-only barrier: drain own LDS ops, barrier, compiler fence both sides.
// vmcnt NOT drained: register-destined global prefetch stays in flight.
#define BAR()                                                        \
    do {                                                             \
        asm volatile("s_waitcnt lgkmcnt(0)" ::: "memory");           \
        __builtin_amdgcn_s_barrier();                                \
        asm volatile("" ::: "memory");                               \
    } while (0)

__device__ __forceinline__ float rcp_f(float v) { return __builtin_amdgcn_rcpf(v); }
#if __has_builtin(__builtin_amdgcn_exp2f)
__device__ __forceinline__ float exp2_f(float v) { return __builtin_amdgcn_exp2f(v); }
#else
__device__ __forceinline__ float exp2_f(float v) { return __expf(0.6931471805599453f * v); }
#endif

__launch_bounds__(512, 4)
__global__ void lstm_fused(const float* __restrict__ x,
                           const float* __restrict__ Wx,
                           const float* __restrict__ Wh,
                           const float* __restrict__ b,
                           const float* __restrict__ W1,
                           const float* __restrict__ b1,
                           const float* __restrict__ W2,
                           const float* __restrict__ b2,
                           float* __restrict__ out)
{
    __shared__ alignas(16) _Float16 xb[2][16][72];        // xb[t&1] = x(t)
    __shared__ alignas(16) _Float16 hb[2][16][72];        // hb[t&1] = h(t)
    __shared__ alignas(16) float axb[2][4][4][64][4];     // [P][tile][gate][lane][4]
    __shared__ float hrelu[16][HEAD_N];

    const int tid  = threadIdx.x;
    const int lane = tid & 63;
    const int w    = tid >> 6;         // 0..7; 0-3 x-waves, 4-7 h-waves
    const int ut   = w & 3;            // unit-tile (16 units each)
    const int rowA = lane & 15;        // A-frag row == C-frag col
    const int kg   = lane >> 4;        // k-group 0..3
    const int R0   = blockIdx.x * 16;  // batch rows of this block
    const int jl   = ut * 16 + rowA;   // unit index 0..63
    const bool jv  = (jl < H_N);

    // ---- role-specific weight fragments (VGPR-resident, exp2-prescaled) --
    f16x8 wxf[4][2], whf[4][2];
    float bg[4];
    if (w < 4) {
        #pragma unroll
        for (int g = 0; g < 4; ++g) {
            const float sc = (g == 2) ? LOG2E2 : LOG2E;
            bg[g] = jv ? b[g * H_N + jl] * sc : 0.0f;
            #pragma unroll
            for (int ks = 0; ks < 2; ++ks) {
                f16x8 v;
                #pragma unroll
                for (int i = 0; i < 8; ++i) {
                    int k = ks * 32 + kg * 8 + i;     // same k-map as A-frags
                    v[i] = (_Float16)(jv ? Wx[k * 200 + g * H_N + jl] * sc : 0.0f);
                }
                wxf[g][ks] = v;
            }
        }
    } else {
        #pragma unroll
        for (int g = 0; g < 4; ++g) {
            const float sc = (g == 2) ? LOG2E2 : LOG2E;
            #pragma unroll
            for (int ks = 0; ks < 2; ++ks) {
                f16x8 v;
                #pragma unroll
                for (int i = 0; i < 8; ++i) {
                    int k = ks * 32 + kg * 8 + i;
                    v[i] = (_Float16)((jv && k < H_N) ? Wh[k * 200 + g * H_N + jl] * sc : 0.0f);
                }
                whf[g][ks] = v;
            }
        }
    }

    float c0 = 0.f, c1 = 0.f, c2 = 0.f, c3 = 0.f;   // h-wave fp32 cell state

    // zero h(0)
    for (int idx = tid; idx < 16 * 72; idx += 512)
        ((_Float16*)hb[0])[idx] = (_Float16)0.0f;

    // x staging map (x-waves = tid 0..255): (row tid>>4, 4 floats), coalesced
    const int xr  = (tid >> 4) & 15;
    const int xf0 = (tid & 15) * 4;
    const float* xrow = x + (size_t)(R0 + xr) * ROWSTRIDE + xf0;
    f32x4 xpr0, xpr1;     // in-flight x rows: xpr[t&1] LDS-written at step t
    if (w < 4) {
        f32x4 v0 = *reinterpret_cast<const f32x4*>(xrow);
        f32x4 v1 = *reinterpret_cast<const f32x4*>(xrow + F_N);
        xpr0 = *reinterpret_cast<const f32x4*>(xrow + 2 * F_N);   // x(2)
        xpr1 = *reinterpret_cast<const f32x4*>(xrow + 3 * F_N);   // x(3)
        f16x4 a, c4;
        #pragma unroll
        for (int j = 0; j < 4; ++j) { a[j] = (_Float16)v0[j]; c4[j] = (_Float16)v1[j]; }
        *reinterpret_cast<f16x4*>(&xb[0][xr][xf0]) = a;   // x(0)
        *reinterpret_cast<f16x4*>(&xb[1][xr][xf0]) = c4;  // x(1)
    }
    const float* xld = xrow + 4 * F_N;   // next global load: x(4)
    __syncthreads();

    if (w < 4) {   // prologue: ax(0) = b + x(0)@Wx -> axb[0]
        f16x8 xa0 = *reinterpret_cast<const f16x8*>(&xb[0][rowA][kg * 8]);
        f16x8 xa1 = *reinterpret_cast<const f16x8*>(&xb[0][rowA][32 + kg * 8]);
        f32x4 a0 = {bg[0], bg[0], bg[0], bg[0]};
        f32x4 a1 = {bg[1], bg[1], bg[1], bg[1]};
        f32x4 a2 = {bg[2], bg[2], bg[2], bg[2]};
        f32x4 a3 = {bg[3], bg[3], bg[3], bg[3]};
        a0 = MFMA(xa0, wxf[0][0], a0, 0, 0, 0);
        a1 = MFMA(xa0, wxf[1][0], a1, 0, 0, 0);
        a2 = MFMA(xa0, wxf[2][0], a2, 0, 0, 0);
        a3 = MFMA(xa0, wxf[3][0], a3, 0, 0, 0);
        a0 = MFMA(xa1, wxf[0][1], a0, 0, 0, 0);
        a1 = MFMA(xa1, wxf[1][1], a1, 0, 0, 0);
        a2 = MFMA(xa1, wxf[2][1], a2, 0, 0, 0);
        a3 = MFMA(xa1, wxf[3][1], a3, 0, 0, 0);
        *reinterpret_cast<f32x4*>(&axb[0][ut][0][lane][0]) = a0;
        *reinterpret_cast<f32x4*>(&axb[0][ut][1][lane][0]) = a1;
        *reinterpret_cast<f32x4*>(&axb[0][ut][2][lane][0]) = a2;
        *reinterpret_cast<f32x4*>(&axb[0][ut][3][lane][0]) = a3;
    }
    __syncthreads();

    // gates v2: merged-rcp pairs, exp2 domain (weights prescaled; g by 2x).
    //   si*tg = (1-B)/((1+A)(1+B)),  A=2^-zi, B=2^-zg  (zg holds 2*log2e*g)
    //   so*tc = (1-D)/((1+C)(1+D)),  C=2^-zo, D=2^eD, eD=min(-2.885*c', 80)
    // Limits: c'->+inf: D->0, h->so.  c'->-inf: D=2^80, h->-so. No inf/NaN.
#define GATE1(PW, ii, cvar)                                                    \
    {                                                                          \
        float A_ = exp2_f(-zi[ii]);                                            \
        float B_ = exp2_f(-zg[ii]);                                            \
        float F_ = exp2_f(-zf[ii]);                                            \
        float sf_ = rcp_f(1.0f + F_);                                          \
        float r1_ = rcp_f((1.0f + A_) * (1.0f + B_));                          \
        float cn_ = fmaf(sf_, cvar, (1.0f - B_) * r1_);                        \
        cvar = cn_;                                                            \
        float C_ = exp2_f(-zo[ii]);                                            \
        float eD_ = fminf(-LOG2E2 * cn_, 80.0f);                               \
        float D_ = exp2_f(eD_);                                                \
        float r2_ = rcp_f((1.0f + C_) * (1.0f + D_));                          \
        hb[PW][kg * 4 + ii][jl] = (_Float16)((1.0f - D_) * r2_);               \
    }

    // x-wave step t (P=t&1): ax(t+1) -> axb[P^1] (reads xb[P^1] = x(t+1));
    // LDS-write x(t+2) -> xb[P]; issue load x(t+4); barrier.
#define XSTEP(P, DO_XW, DO_LOAD)                                               \
    {                                                                          \
        f16x8 xa0 = *reinterpret_cast<const f16x8*>(&xb[P ^ 1][rowA][kg * 8]);      \
        f16x8 xa1 = *reinterpret_cast<const f16x8*>(&xb[P ^ 1][rowA][32 + kg * 8]); \
        f32x4 a0 = {bg[0], bg[0], bg[0], bg[0]};                               \
        f32x4 a1 = {bg[1], bg[1], bg[1], bg[1]};                               \
        f32x4 a2 = {bg[2], bg[2], bg[2], bg[2]};                               \
        f32x4 a3 = {bg[3], bg[3], bg[3], bg[3]};                               \
        a0 = MFMA(xa0, wxf[0][0], a0, 0, 0, 0);                                \
        a1 = MFMA(xa0, wxf[1][0], a1, 0, 0, 0);                                \
        a2 = MFMA(xa0, wxf[2][0], a2, 0, 0, 0);                                \
        a3 = MFMA(xa0, wxf[3][0], a3, 0, 0, 0);                                \
        a0 = MFMA(xa1, wxf[0][1], a0, 0, 0, 0);                                \
        a1 = MFMA(xa1, wxf[1][1], a1, 0, 0, 0);                                \
        a2 = MFMA(xa1, wxf[2][1], a2, 0, 0, 0);                                \
        a3 = MFMA(xa1, wxf[3][1], a3, 0, 0, 0);                                \
        *reinterpret_cast<f32x4*>(&axb[P ^ 1][ut][0][lane][0]) = a0;           \
        *reinterpret_cast<f32x4*>(&axb[P ^ 1][ut][1][lane][0]) = a1;           \
        *reinterpret_cast<f32x4*>(&axb[P ^ 1][ut][2][lane][0]) = a2;           \
        *reinterpret_cast<f32x4*>(&axb[P ^ 1][ut][3][lane][0]) = a3;           \
        if (DO_XW) {                                                           \
            f16x4 xc;                                                          \
            xc[0] = (_Float16)xpr##P[0]; xc[1] = (_Float16)xpr##P[1];          \
            xc[2] = (_Float16)xpr##P[2]; xc[3] = (_Float16)xpr##P[3];          \
            *reinterpret_cast<f16x4*>(&xb[P][xr][xf0]) = xc;                   \
        }                                                                      \
        if (DO_LOAD) { xpr##P = *reinterpret_cast<const f32x4*>(xld); xld += F_N; } \
        BAR();                                                                 \
    }

    // h-wave step t (P=t&1): z = axb[P] + h(t)@Wh; gates; h(t+1) -> hb[P^1].
#define HSTEP(P)                                                               \
    {                                                                          \
        __builtin_amdgcn_s_setprio(1);                                         \
        f16x8 ha0 = *reinterpret_cast<const f16x8*>(&hb[P][rowA][kg * 8]);     \
        f16x8 ha1 = *reinterpret_cast<const f16x8*>(&hb[P][rowA][32 + kg * 8]);\
        f32x4 zi = *reinterpret_cast<const f32x4*>(&axb[P][ut][0][lane][0]);   \
        f32x4 zf = *reinterpret_cast<const f32x4*>(&axb[P][ut][1][lane][0]);   \
        f32x4 zg = *reinterpret_cast<const f32x4*>(&axb[P][ut][2][lane][0]);   \
        f32x4 zo = *reinterpret_cast<const f32x4*>(&axb[P][ut][3][lane][0]);   \
        zi = MFMA(ha0, whf[0][0], zi, 0, 0, 0);                                \
        zf = MFMA(ha0, whf[1][0], zf, 0, 0, 0);                                \
        zg = MFMA(ha0, whf[2][0], zg, 0, 0, 0);                                \
        zo = MFMA(ha0, whf[3][0], zo, 0, 0, 0);                                \
        zi = MFMA(ha1, whf[0][1], zi, 0, 0, 0);                                \
        zf = MFMA(ha1, whf[1][1], zf, 0, 0, 0);                                \
        zg = MFMA(ha1, whf[2][1], zg, 0, 0, 0);                                \
        zo = MFMA(ha1, whf[3][1], zo, 0, 0, 0);                                \
        GATE1(P ^ 1, 0, c0)                                                    \
        GATE1(P ^ 1, 1, c1)                                                    \
        GATE1(P ^ 1, 2, c2)                                                    \
        GATE1(P ^ 1, 3, c3)                                                    \
        __builtin_amdgcn_s_setprio(0);                                         \
        BAR();                                                                 \
    }

    // Both role-loops execute EXACTLY 168 barriers (mirror structure).
    if (w < 4) {
        for (int it = 0; it < 82; ++it) {   // t = 0..163
            XSTEP(0, 1, 1)
            XSTEP(1, 1, 1)
        }
        XSTEP(0, 1, 0)   // t=164: ax(165), write x(166)
        XSTEP(1, 1, 0)   // t=165: ax(166), write x(167)
        XSTEP(0, 0, 0)   // t=166: ax(167)
        BAR();           // t=167: x-waves just sync
    } else {
        for (int it = 0; it < 82; ++it) {   // t = 0..163
            HSTEP(0)
            HSTEP(1)
        }
        HSTEP(0)   // t=164
        HSTEP(1)   // t=165
        HSTEP(0)   // t=166
        HSTEP(1)   // t=167: final h(168) -> hb[0]
    }
#undef XSTEP
#undef HSTEP
#undef GATE1

    // ---- MLP head: relu(h@W1 + b1)@W2 + b2 + x[:, -1, 0] ------------------
    if (tid < 256) {
        const int r1 = tid & 15;
        const int u1 = tid >> 4;
        float hrow[H_N];
        #pragma unroll
        for (int k = 0; k < H_N; ++k) hrow[k] = (float)hb[0][r1][k];
        for (int uu = u1; uu < HEAD_N; uu += 16) {
            float s = b1[uu];
            #pragma unroll
            for (int k = 0; k < H_N; ++k) s += hrow[k] * W1[k * HEAD_N + uu];
            hrelu[r1][uu] = fmaxf(s, 0.0f);
        }
    }
    __syncthreads();
    if (tid < 256) {
        const int r2 = tid >> 4;
        const int p  = tid & 15;
        float s = 0.0f;
        for (int uu = p; uu < HEAD_N; uu += 16) s += hrelu[r2][uu] * W2[uu];
        #pragma unroll
        for (int off = 8; off > 0; off >>= 1) s += __shfl_xor(s, off, 16);
        if (p == 0) {
            float res = x[(size_t)(R0 + r2) * ROWSTRIDE + (T_N - 1) * F_N + 0];
            out[R0 + r2] = s + b2[0] + res;
        }
    }
}

extern "C" void kernel_launch(void* const* d_in, const int* in_sizes, int n_in,
                              void* d_out, int out_size, void* d_ws, size_t ws_size,
                              hipStream_t stream) {
    const float* x  = (const float*)d_in[0];
    const float* Wx = (const float*)d_in[1];
    const float* Wh = (const float*)d_in[2];
    const float* b  = (const float*)d_in[3];
    const float* W1 = (const float*)d_in[4];
    const float* b1 = (const float*)d_in[5];
    const float* W2 = (const float*)d_in[6];
    const float* b2 = (const float*)d_in[7];
    float* out = (float*)d_out;

    lstm_fused<<<dim3(B_N / 16), dim3(512), 0, stream>>>(x, Wx, Wh, b, W1, b1, W2, b2, out);
}